// Round 1
// baseline (120.217 us; speedup 1.0000x reference)
//
#include <hip/hip_runtime.h>
#include <math.h>

#define BB 16
#define NN 128
#define DD 128
#define NEGV (-9e15f)
#define SLOPE 0.2f

// ---------------- K1: typed Q projection ----------------
// q[r,:] = (t==0) ? 0 : hidden[r,:] @ W_Q[t]   (t = node_type_mask[r])
__global__ __launch_bounds__(128) void hete_qproj(
    const float* __restrict__ hidden, const int* __restrict__ mask,
    const float* __restrict__ WQ, float* __restrict__ q)
{
    const int r = blockIdx.x;      // 0..2047 global row
    const int d = threadIdx.x;     // 0..127
    __shared__ float h[DD];
    h[d] = hidden[r * DD + d];
    __syncthreads();
    const int t = mask[r];         // uniform per block
    if (t == 0) { q[r * DD + d] = 0.f; return; }
    const float* W = WQ + t * DD * DD;
    float acc = 0.f;
#pragma unroll 8
    for (int k = 0; k < DD; ++k)
        acc = fmaf(h[k], W[k * DD + d], acc);
    q[r * DD + d] = acc;
}

// ---------------- K2: fused attention (homo/hete/global) + gate MLPs ----------------
// grid = B * 32 chunks (4 rows per block), block = 256 threads.
__global__ __launch_bounds__(256) void hete_fused(
    const float* __restrict__ q, const int* __restrict__ adj,
    const float* __restrict__ aparam,
    const float* __restrict__ p_w1, const float* __restrict__ p_b1,
    const float* __restrict__ p_w2, const float* __restrict__ p_b2,
    const float* __restrict__ g_w1, const float* __restrict__ g_b1,
    const float* __restrict__ g_w2, const float* __restrict__ g_b2,
    float* __restrict__ out)
{
    __shared__ float qs[NN][DD];              // XOR-swizzled: qs[j][d ^ (j&31)]
    __shared__ float a_s[4][132];             // edge-type vectors, padded
    __shared__ float wrow[2][3][NN];          // per row-pair: [eh][homoW/heteW/tanh][j]
    __shared__ float red[4][8];               // cross-wave reduction scratch
    __shared__ float enr[8];                  // MLP energies (8 evals)
    __shared__ __align__(16) float ro[4][3][132]; // row outputs: homo/hete/global (slot0 becomes local)

    const int tid  = threadIdx.x;
    const int b    = blockIdx.x >> 5;         // batch
    const int chunk= blockIdx.x & 31;         // 4-row chunk
    const int eh   = tid >> 7;                // which of 2 concurrent rows
    const int j    = tid & 127;
    const int wv   = tid >> 6;                // wave 0..3
    const int lane = tid & 63;

    // ---- stage q[b] (swizzled) and a ----
    const float* qb = q + b * NN * DD;
    for (int it = 0; it < (NN * DD) / 256; ++it) {
        int idx = it * 256 + tid;
        int jj = idx >> 7, dd = idx & 127;
        qs[jj][dd ^ (jj & 31)] = qb[idx];
    }
    for (int it = 0; it < 2; ++it) {
        int idx = it * 256 + tid;
        a_s[idx >> 7][idx & 127] = aparam[idx];
    }
    __syncthreads();

    // ---- attention: 2 row-pairs ----
    for (int rp = 0; rp < 2; ++rp) {
        const int rL = rp * 2 + eh;           // block-local row 0..3
        const int ri = chunk * 4 + rL;        // batch-local row 0..127
        const int adjv = adj[(b * NN + ri) * NN + j];
        const bool inH = (adjv >= 1 && adjv <= 4);
        const bool inT = (adjv == 1) || (adjv >= 5);   // adj <= 10 always
        const int  rh  = inH ? (adjv - 1) : 0;
        const int  risw = ri & 31;

        float s = 0.f, hm = 0.f;
#pragma unroll 4
        for (int d = 0; d < DD; ++d) {
            float qi = qs[ri][d ^ risw];       // wave-uniform broadcast
            float qj = qs[j][d ^ (j & 31)];
            float p  = qi * qj;
            s += p;
            hm = fmaf(p, a_s[rh][d], hm);
        }

        float gw = tanhf(s);                                   // global path
        float aH = inH ? (hm > 0.f ? hm : SLOPE * hm) : NEGV;  // homo: lrelu then mask
        float sT = inT ? s : NEGV;                             // hete: mask then lrelu
        sT = (sT > 0.f) ? sT : SLOPE * sT;

        // softmax over the 128 j's (2 waves per row)
        float mH = aH, mT = sT;
        for (int off = 32; off; off >>= 1) {
            mH = fmaxf(mH, __shfl_xor(mH, off));
            mT = fmaxf(mT, __shfl_xor(mT, off));
        }
        if (lane == 0) { red[wv][0] = mH; red[wv][1] = mT; }
        __syncthreads();
        mH = fmaxf(red[eh * 2][0], red[eh * 2 + 1][0]);
        mT = fmaxf(red[eh * 2][1], red[eh * 2 + 1][1]);
        float eHv = expf(aH - mH);
        float eTv = expf(sT - mT);
        float sumH = eHv, sumT = eTv;
        for (int off = 32; off; off >>= 1) {
            sumH += __shfl_xor(sumH, off);
            sumT += __shfl_xor(sumT, off);
        }
        __syncthreads();   // all max-reads done before red reuse
        if (lane == 0) { red[wv][0] = sumH; red[wv][1] = sumT; }
        __syncthreads();
        sumH = red[eh * 2][0] + red[eh * 2 + 1][0];
        sumT = red[eh * 2][1] + red[eh * 2 + 1][1];
        wrow[eh][0][j] = eHv / sumH;
        wrow[eh][1][j] = eTv / sumT;
        wrow[eh][2][j] = gw;
        __syncthreads();

        // weighted sums: thread d accumulates over j
        const int d = j;
        float accH = 0.f, accT = 0.f, accG = 0.f;
#pragma unroll 4
        for (int jj = 0; jj < NN; ++jj) {
            float qv = qs[jj][d ^ (jj & 31)];
            accH = fmaf(wrow[eh][0][jj], qv, accH);
            accT = fmaf(wrow[eh][1][jj], qv, accT);
            accG = fmaf(wrow[eh][2][jj], qv, accG);
        }
        ro[rL][0][d] = accH;
        ro[rL][1][d] = accT;
        ro[rL][2][d] = accG;
        __syncthreads();
    }

    // ---- gate stage 1: p-MLP on (row, {homo,hete}), 8 evals, 4 per thread ----
    const int u = j;   // hidden unit
    {
        float a0 = 0.f, a1 = 0.f, a2 = 0.f, a3 = 0.f;
        for (int k = 0; k < DD; k += 4) {
            float w0 = p_w1[(k + 0) * DD + u];
            float w1 = p_w1[(k + 1) * DD + u];
            float w2 = p_w1[(k + 2) * DD + u];
            float w3 = p_w1[(k + 3) * DD + u];
            const float4 x0 = *reinterpret_cast<const float4*>(&ro[eh * 2 + 0][0][k]);
            const float4 x1 = *reinterpret_cast<const float4*>(&ro[eh * 2 + 0][1][k]);
            const float4 x2 = *reinterpret_cast<const float4*>(&ro[eh * 2 + 1][0][k]);
            const float4 x3 = *reinterpret_cast<const float4*>(&ro[eh * 2 + 1][1][k]);
            a0 = fmaf(x0.x, w0, fmaf(x0.y, w1, fmaf(x0.z, w2, fmaf(x0.w, w3, a0))));
            a1 = fmaf(x1.x, w0, fmaf(x1.y, w1, fmaf(x1.z, w2, fmaf(x1.w, w3, a1))));
            a2 = fmaf(x2.x, w0, fmaf(x2.y, w1, fmaf(x2.z, w2, fmaf(x2.w, w3, a2))));
            a3 = fmaf(x3.x, w0, fmaf(x3.y, w1, fmaf(x3.z, w2, fmaf(x3.w, w3, a3))));
        }
        float pb1 = p_b1[u], pw2 = p_w2[u];
        float c0 = fmaxf(a0 + pb1, 0.f) * pw2;
        float c1 = fmaxf(a1 + pb1, 0.f) * pw2;
        float c2 = fmaxf(a2 + pb1, 0.f) * pw2;
        float c3 = fmaxf(a3 + pb1, 0.f) * pw2;
        for (int off = 32; off; off >>= 1) {
            c0 += __shfl_xor(c0, off);
            c1 += __shfl_xor(c1, off);
            c2 += __shfl_xor(c2, off);
            c3 += __shfl_xor(c3, off);
        }
        if (lane == 0) { red[wv][0] = c0; red[wv][1] = c1; red[wv][2] = c2; red[wv][3] = c3; }
    }
    __syncthreads();
    if (tid < 8) {
        int half = tid >> 2;   // evals 0..3 from waves 0,1 ; 4..7 from waves 2,3
        enr[tid] = red[half * 2][tid & 3] + red[half * 2 + 1][tid & 3] + p_b2[0];
    }
    __syncthreads();
    // local = softmax2(e_homo, e_hete) · (homo, hete)  — overwrite slot 0
#pragma unroll
    for (int rr = 0; rr < 2; ++rr) {
        int rL = eh * 2 + rr;
        float e0 = enr[rL * 2], e1 = enr[rL * 2 + 1];
        float m  = fmaxf(e0, e1);
        float x0 = expf(e0 - m), x1 = expf(e1 - m);
        float inv = 1.f / (x0 + x1);
        ro[rL][0][u] = (x0 * ro[rL][0][u] + x1 * ro[rL][1][u]) * inv;
    }
    __syncthreads();

    // ---- gate stage 2: g-MLP on (row, {local,global}) ----
    {
        float a0 = 0.f, a1 = 0.f, a2 = 0.f, a3 = 0.f;
        for (int k = 0; k < DD; k += 4) {
            float w0 = g_w1[(k + 0) * DD + u];
            float w1 = g_w1[(k + 1) * DD + u];
            float w2 = g_w1[(k + 2) * DD + u];
            float w3 = g_w1[(k + 3) * DD + u];
            const float4 x0 = *reinterpret_cast<const float4*>(&ro[eh * 2 + 0][0][k]);
            const float4 x1 = *reinterpret_cast<const float4*>(&ro[eh * 2 + 0][2][k]);
            const float4 x2 = *reinterpret_cast<const float4*>(&ro[eh * 2 + 1][0][k]);
            const float4 x3 = *reinterpret_cast<const float4*>(&ro[eh * 2 + 1][2][k]);
            a0 = fmaf(x0.x, w0, fmaf(x0.y, w1, fmaf(x0.z, w2, fmaf(x0.w, w3, a0))));
            a1 = fmaf(x1.x, w0, fmaf(x1.y, w1, fmaf(x1.z, w2, fmaf(x1.w, w3, a1))));
            a2 = fmaf(x2.x, w0, fmaf(x2.y, w1, fmaf(x2.z, w2, fmaf(x2.w, w3, a2))));
            a3 = fmaf(x3.x, w0, fmaf(x3.y, w1, fmaf(x3.z, w2, fmaf(x3.w, w3, a3))));
        }
        float gb1 = g_b1[u], gw2 = g_w2[u];
        float c0 = fmaxf(a0 + gb1, 0.f) * gw2;
        float c1 = fmaxf(a1 + gb1, 0.f) * gw2;
        float c2 = fmaxf(a2 + gb1, 0.f) * gw2;
        float c3 = fmaxf(a3 + gb1, 0.f) * gw2;
        for (int off = 32; off; off >>= 1) {
            c0 += __shfl_xor(c0, off);
            c1 += __shfl_xor(c1, off);
            c2 += __shfl_xor(c2, off);
            c3 += __shfl_xor(c3, off);
        }
        __syncthreads();   // all enr reads (local loop) done before red reuse
        if (lane == 0) { red[wv][0] = c0; red[wv][1] = c1; red[wv][2] = c2; red[wv][3] = c3; }
    }
    __syncthreads();
    if (tid < 8) {
        int half = tid >> 2;
        enr[tid] = red[half * 2][tid & 3] + red[half * 2 + 1][tid & 3] + g_b2[0];
    }
    __syncthreads();
    // final = softmax2(e_local, e_global) · (local, global)
#pragma unroll
    for (int rr = 0; rr < 2; ++rr) {
        int rL = eh * 2 + rr;
        float e0 = enr[rL * 2], e1 = enr[rL * 2 + 1];
        float m  = fmaxf(e0, e1);
        float x0 = expf(e0 - m), x1 = expf(e1 - m);
        float inv = 1.f / (x0 + x1);
        float val = (x0 * ro[rL][0][u] + x1 * ro[rL][2][u]) * inv;
        out[(b * NN + chunk * 4 + rL) * DD + u] = val;
    }
}

extern "C" void kernel_launch(void* const* d_in, const int* in_sizes, int n_in,
                              void* d_out, int out_size, void* d_ws, size_t ws_size,
                              hipStream_t stream) {
    const float* hidden = (const float*)d_in[0];
    const int*   adj    = (const int*)d_in[1];
    const int*   mask   = (const int*)d_in[2];
    const float* W_Q    = (const float*)d_in[3];
    // d_in[4] = W_K, d_in[5] = W_V — unused (source bug preserved: k = v = q)
    const float* aparam = (const float*)d_in[6];
    const float* p_w1   = (const float*)d_in[7];
    const float* p_b1   = (const float*)d_in[8];
    const float* p_w2   = (const float*)d_in[9];
    const float* p_b2   = (const float*)d_in[10];
    const float* g_w1   = (const float*)d_in[11];
    const float* g_b1   = (const float*)d_in[12];
    const float* g_w2   = (const float*)d_in[13];
    const float* g_b2   = (const float*)d_in[14];
    float* out = (float*)d_out;
    float* qws = (float*)d_ws;          // [2048][128] f32 = 1 MB

    hete_qproj<<<BB * NN, 128, 0, stream>>>(hidden, mask, W_Q, qws);
    hete_fused<<<BB * 32, 256, 0, stream>>>(qws, adj, aparam,
                                            p_w1, p_b1, p_w2, p_b2,
                                            g_w1, g_b1, g_w2, g_b2, out);
}

// Round 2
// 111.575 us; speedup vs baseline: 1.0775x; 1.0775x over previous
//
#include <hip/hip_runtime.h>
#include <math.h>

#define BB 16
#define NN 128
#define DD 128
#define NEGV (-9e15f)
#define SLOPE 0.2f

__device__ __forceinline__ float fast_tanh(float x) {
    // tanh(x) = 1 - 2/(e^{2x}+1); matches tanhf to ~1e-6, saturates correctly
    float e = __expf(2.f * x);
    return 1.f - 2.f / (e + 1.f);
}

// ---------------- K1: typed Q projection ----------------
// q[r,:] = (t==0) ? 0 : hidden[r,:] @ W_Q[t]
__global__ __launch_bounds__(128) void hete_qproj(
    const float* __restrict__ hidden, const int* __restrict__ mask,
    const float* __restrict__ WQ, float* __restrict__ q)
{
    const int r = blockIdx.x;
    const int d = threadIdx.x;
    __shared__ float h[DD];
    h[d] = hidden[r * DD + d];
    __syncthreads();
    const int t = mask[r];
    if (t == 0) { q[r * DD + d] = 0.f; return; }
    const float* W = WQ + t * DD * DD;
    float acc = 0.f;
#pragma unroll 8
    for (int k = 0; k < DD; ++k)
        acc = fmaf(h[k], W[k * DD + d], acc);
    q[r * DD + d] = acc;
}

// ---------------- K2: fused attention + gates ----------------
// grid = B*32 (4 rows/block), 256 threads = 4 waves, ONE ROW PER WAVE.
__global__ __launch_bounds__(256) void hete_fused(
    const float* __restrict__ q, const int* __restrict__ adj,
    const float* __restrict__ aparam,
    const float* __restrict__ p_w1, const float* __restrict__ p_b1,
    const float* __restrict__ p_w2, const float* __restrict__ p_b2,
    const float* __restrict__ g_w1, const float* __restrict__ g_b1,
    const float* __restrict__ g_w2, const float* __restrict__ g_b2,
    float* __restrict__ out)
{
    // qs: float4-granular XOR swizzle — element (j, d) at qs[j][((d>>2)^(j&31))*4 + (d&3)]
    // conflict-free b128 for both "fixed d4, vary j" (score) and "fixed j, vary d4" (wsum)
    __shared__ float qs[NN][DD];          // 64 KB, later reused for W1 staging
    __shared__ float a_s[4][132];         // stride 132: 4 rows on disjoint bank quads
    __shared__ float4 wreg[4][NN];        // per-wave: w packed (wH,wT,tanh,-); later row outputs
    __shared__ float red[4][8];
    __shared__ float enr[8];

    const int tid   = threadIdx.x;
    const int b     = blockIdx.x >> 5;
    const int chunk = blockIdx.x & 31;
    const int wv    = tid >> 6;
    const int lane  = tid & 63;
    const int eh    = tid >> 7;
    const int u     = tid & 127;

    // ---- stage q[b] (swizzled, float4) + a ----
    const float4* qb4 = (const float4*)(q + b * NN * DD);
#pragma unroll
    for (int it = 0; it < 16; ++it) {
        int i4 = it * 256 + tid;          // 0..4095
        int jj = i4 >> 5, d4 = i4 & 31;
        *(float4*)&qs[jj][(d4 ^ (jj & 31)) << 2] = qb4[i4];
    }
#pragma unroll
    for (int it = 0; it < 2; ++it) {
        int idx = it * 256 + tid;         // 0..511
        a_s[idx >> 7][idx & 127] = aparam[idx];
    }
    __syncthreads();

    // ---- attention: one row per wave, lanes cover j = lane, lane+64 ----
    const int ri = chunk * 4 + wv;
    const int j0 = lane, j1 = lane + 64;
    const int* adjRow = adj + (b * NN + ri) * NN;
    const int av0 = adjRow[j0], av1 = adjRow[j1];
    const bool inH0 = (av0 >= 1) & (av0 <= 4);
    const bool inH1 = (av1 >= 1) & (av1 <= 4);
    const bool inT0 = (av0 == 1) | (av0 >= 5);
    const bool inT1 = (av1 == 1) | (av1 >= 5);
    const float* aA = &a_s[inH0 ? av0 - 1 : 0][0];
    const float* aB = &a_s[inH1 ? av1 - 1 : 0][0];
    const int risw = ri & 31;
    const int jsw  = lane & 31;           // == j1 & 31
    const float* qiB = &qs[ri][0];
    const float* qaB = &qs[j0][0];
    const float* qbB = &qs[j1][0];

    float s0 = 0.f, s1 = 0.f, hm0 = 0.f, hm1 = 0.f;
#pragma unroll 4
    for (int d4 = 0; d4 < 32; ++d4) {
        float4 qi = *(const float4*)(qiB + ((d4 ^ risw) << 2));   // broadcast
        float4 qa = *(const float4*)(qaB + ((d4 ^ jsw) << 2));
        float4 qb = *(const float4*)(qbB + ((d4 ^ jsw) << 2));
        float4 av = *(const float4*)(aA + (d4 << 2));
        float4 bv = *(const float4*)(aB + (d4 << 2));
        float p;
        p = qi.x * qa.x; s0 += p; hm0 = fmaf(p, av.x, hm0);
        p = qi.y * qa.y; s0 += p; hm0 = fmaf(p, av.y, hm0);
        p = qi.z * qa.z; s0 += p; hm0 = fmaf(p, av.z, hm0);
        p = qi.w * qa.w; s0 += p; hm0 = fmaf(p, av.w, hm0);
        p = qi.x * qb.x; s1 += p; hm1 = fmaf(p, bv.x, hm1);
        p = qi.y * qb.y; s1 += p; hm1 = fmaf(p, bv.y, hm1);
        p = qi.z * qb.z; s1 += p; hm1 = fmaf(p, bv.z, hm1);
        p = qi.w * qb.w; s1 += p; hm1 = fmaf(p, bv.w, hm1);
    }

    float gw0 = fast_tanh(s0), gw1 = fast_tanh(s1);
    float aH0 = inH0 ? (hm0 > 0.f ? hm0 : SLOPE * hm0) : NEGV;   // homo: lrelu then mask
    float aH1 = inH1 ? (hm1 > 0.f ? hm1 : SLOPE * hm1) : NEGV;
    float t0 = inT0 ? s0 : NEGV; t0 = (t0 > 0.f) ? t0 : SLOPE * t0;  // hete: mask then lrelu
    float t1 = inT1 ? s1 : NEGV; t1 = (t1 > 0.f) ? t1 : SLOPE * t1;

    // in-wave softmax over 128 (2 vals/lane + 6-step butterfly)
    float mH = fmaxf(aH0, aH1), mT = fmaxf(t0, t1);
#pragma unroll
    for (int off = 32; off; off >>= 1) {
        mH = fmaxf(mH, __shfl_xor(mH, off));
        mT = fmaxf(mT, __shfl_xor(mT, off));
    }
    float eH0 = __expf(aH0 - mH), eH1 = __expf(aH1 - mH);
    float eT0 = __expf(t0 - mT),  eT1 = __expf(t1 - mT);
    float sH = eH0 + eH1, sT = eT0 + eT1;
#pragma unroll
    for (int off = 32; off; off >>= 1) {
        sH += __shfl_xor(sH, off);
        sT += __shfl_xor(sT, off);
    }
    float invH = 1.f / sH, invT = 1.f / sT;
    wreg[wv][j0] = make_float4(eH0 * invH, eT0 * invT, gw0, 0.f);
    wreg[wv][j1] = make_float4(eH1 * invH, eT1 * invT, gw1, 0.f);
    __syncthreads();

    // ---- weighted sums: lane owns d4=l5; halves split the j range ----
    const int half = lane >> 5, l5 = lane & 31;
    float4 acH = make_float4(0,0,0,0), acT = make_float4(0,0,0,0), acG = make_float4(0,0,0,0);
#pragma unroll 4
    for (int jj = 0; jj < 64; ++jj) {
        int j = half * 64 + jj;
        float4 w4 = wreg[wv][j];                                   // 2-addr broadcast
        float4 qv = *(const float4*)(&qs[j][0] + ((l5 ^ (j & 31)) << 2));
        acH.x = fmaf(w4.x, qv.x, acH.x); acH.y = fmaf(w4.x, qv.y, acH.y);
        acH.z = fmaf(w4.x, qv.z, acH.z); acH.w = fmaf(w4.x, qv.w, acH.w);
        acT.x = fmaf(w4.y, qv.x, acT.x); acT.y = fmaf(w4.y, qv.y, acT.y);
        acT.z = fmaf(w4.y, qv.z, acT.z); acT.w = fmaf(w4.y, qv.w, acT.w);
        acG.x = fmaf(w4.z, qv.x, acG.x); acG.y = fmaf(w4.z, qv.y, acG.y);
        acG.z = fmaf(w4.z, qv.z, acG.z); acG.w = fmaf(w4.z, qv.w, acG.w);
    }
    acH.x += __shfl_xor(acH.x, 32); acH.y += __shfl_xor(acH.y, 32);
    acH.z += __shfl_xor(acH.z, 32); acH.w += __shfl_xor(acH.w, 32);
    acT.x += __shfl_xor(acT.x, 32); acT.y += __shfl_xor(acT.y, 32);
    acT.z += __shfl_xor(acT.z, 32); acT.w += __shfl_xor(acT.w, 32);
    acG.x += __shfl_xor(acG.x, 32); acG.y += __shfl_xor(acG.y, 32);
    acG.z += __shfl_xor(acG.z, 32); acG.w += __shfl_xor(acG.w, 32);
    {   // overwrite this wave's wreg region with row outputs [3][128]
        float* ro = (float*)&wreg[wv][0];
        if (half == 0) {
            *(float4*)&ro[0 * 128 + (l5 << 2)] = acH;
            *(float4*)&ro[1 * 128 + (l5 << 2)] = acT;
            *(float4*)&ro[2 * 128 + (l5 << 2)] = acG;
        }
    }
    __syncthreads();   // all qs reads + ro writes done -> qs reusable, ro visible

    // ---- gate stage 1: stage p_w1 into qs region, MLP on (row, {homo,hete}) ----
    float* wlds = &qs[0][0];
    {
        const float4* pw14 = (const float4*)p_w1;
#pragma unroll
        for (int it = 0; it < 16; ++it) {
            int i4 = it * 256 + tid;
            *(float4*)&wlds[i4 << 2] = pw14[i4];
        }
    }
    __syncthreads();

    const float* roA = (const float*)&wreg[eh * 2 + 0][0];
    const float* roB = (const float*)&wreg[eh * 2 + 1][0];
    {
        float ga0 = 0.f, ga1 = 0.f, ga2 = 0.f, ga3 = 0.f;
#pragma unroll 4
        for (int k = 0; k < DD; k += 4) {
            float w0 = wlds[(k + 0) * DD + u];
            float w1 = wlds[(k + 1) * DD + u];
            float w2 = wlds[(k + 2) * DD + u];
            float w3 = wlds[(k + 3) * DD + u];
            float4 x0 = *(const float4*)&roA[0 * 128 + k];
            float4 x1 = *(const float4*)&roA[1 * 128 + k];
            float4 x2 = *(const float4*)&roB[0 * 128 + k];
            float4 x3 = *(const float4*)&roB[1 * 128 + k];
            ga0 = fmaf(x0.x, w0, fmaf(x0.y, w1, fmaf(x0.z, w2, fmaf(x0.w, w3, ga0))));
            ga1 = fmaf(x1.x, w0, fmaf(x1.y, w1, fmaf(x1.z, w2, fmaf(x1.w, w3, ga1))));
            ga2 = fmaf(x2.x, w0, fmaf(x2.y, w1, fmaf(x2.z, w2, fmaf(x2.w, w3, ga2))));
            ga3 = fmaf(x3.x, w0, fmaf(x3.y, w1, fmaf(x3.z, w2, fmaf(x3.w, w3, ga3))));
        }
        float pb1 = p_b1[u], pw2v = p_w2[u];
        float c0 = fmaxf(ga0 + pb1, 0.f) * pw2v;
        float c1 = fmaxf(ga1 + pb1, 0.f) * pw2v;
        float c2 = fmaxf(ga2 + pb1, 0.f) * pw2v;
        float c3 = fmaxf(ga3 + pb1, 0.f) * pw2v;
#pragma unroll
        for (int off = 32; off; off >>= 1) {
            c0 += __shfl_xor(c0, off); c1 += __shfl_xor(c1, off);
            c2 += __shfl_xor(c2, off); c3 += __shfl_xor(c3, off);
        }
        if (lane == 0) { red[wv][0] = c0; red[wv][1] = c1; red[wv][2] = c2; red[wv][3] = c3; }
    }
    __syncthreads();
    if (tid < 8) {
        int hf = tid >> 2;
        enr[tid] = red[hf * 2][tid & 3] + red[hf * 2 + 1][tid & 3] + p_b2[0];
    }
    __syncthreads();
    // local = softmax2(homo,hete) blend — overwrite slot 0
#pragma unroll
    for (int rr = 0; rr < 2; ++rr) {
        int rL = eh * 2 + rr;
        float* roX = (float*)&wreg[rL][0];
        float e0 = enr[rL * 2], e1 = enr[rL * 2 + 1];
        float m = fmaxf(e0, e1);
        float x0 = __expf(e0 - m), x1 = __expf(e1 - m);
        float inv = 1.f / (x0 + x1);
        roX[0 * 128 + u] = (x0 * roX[0 * 128 + u] + x1 * roX[1 * 128 + u]) * inv;
    }
    // ---- gate stage 2: stage g_w1, MLP on (row, {local,global}) ----
    {
        const float4* gw14 = (const float4*)g_w1;
#pragma unroll
        for (int it = 0; it < 16; ++it) {
            int i4 = it * 256 + tid;
            *(float4*)&wlds[i4 << 2] = gw14[i4];
        }
    }
    __syncthreads();
    {
        float ga0 = 0.f, ga1 = 0.f, ga2 = 0.f, ga3 = 0.f;
#pragma unroll 4
        for (int k = 0; k < DD; k += 4) {
            float w0 = wlds[(k + 0) * DD + u];
            float w1 = wlds[(k + 1) * DD + u];
            float w2 = wlds[(k + 2) * DD + u];
            float w3 = wlds[(k + 3) * DD + u];
            float4 x0 = *(const float4*)&roA[0 * 128 + k];   // local
            float4 x1 = *(const float4*)&roA[2 * 128 + k];   // global
            float4 x2 = *(const float4*)&roB[0 * 128 + k];
            float4 x3 = *(const float4*)&roB[2 * 128 + k];
            ga0 = fmaf(x0.x, w0, fmaf(x0.y, w1, fmaf(x0.z, w2, fmaf(x0.w, w3, ga0))));
            ga1 = fmaf(x1.x, w0, fmaf(x1.y, w1, fmaf(x1.z, w2, fmaf(x1.w, w3, ga1))));
            ga2 = fmaf(x2.x, w0, fmaf(x2.y, w1, fmaf(x2.z, w2, fmaf(x2.w, w3, ga2))));
            ga3 = fmaf(x3.x, w0, fmaf(x3.y, w1, fmaf(x3.z, w2, fmaf(x3.w, w3, ga3))));
        }
        float gb1v = g_b1[u], gw2v = g_w2[u];
        float c0 = fmaxf(ga0 + gb1v, 0.f) * gw2v;
        float c1 = fmaxf(ga1 + gb1v, 0.f) * gw2v;
        float c2 = fmaxf(ga2 + gb1v, 0.f) * gw2v;
        float c3 = fmaxf(ga3 + gb1v, 0.f) * gw2v;
#pragma unroll
        for (int off = 32; off; off >>= 1) {
            c0 += __shfl_xor(c0, off); c1 += __shfl_xor(c1, off);
            c2 += __shfl_xor(c2, off); c3 += __shfl_xor(c3, off);
        }
        if (lane == 0) { red[wv][0] = c0; red[wv][1] = c1; red[wv][2] = c2; red[wv][3] = c3; }
    }
    __syncthreads();
    if (tid < 8) {
        int hf = tid >> 2;
        enr[tid] = red[hf * 2][tid & 3] + red[hf * 2 + 1][tid & 3] + g_b2[0];
    }
    __syncthreads();
#pragma unroll
    for (int rr = 0; rr < 2; ++rr) {
        int rL = eh * 2 + rr;
        const float* roX = (const float*)&wreg[rL][0];
        float e0 = enr[rL * 2], e1 = enr[rL * 2 + 1];
        float m = fmaxf(e0, e1);
        float x0 = __expf(e0 - m), x1 = __expf(e1 - m);
        float inv = 1.f / (x0 + x1);
        float val = (x0 * roX[0 * 128 + u] + x1 * roX[2 * 128 + u]) * inv;
        out[(b * NN + chunk * 4 + rL) * DD + u] = val;
    }
}

extern "C" void kernel_launch(void* const* d_in, const int* in_sizes, int n_in,
                              void* d_out, int out_size, void* d_ws, size_t ws_size,
                              hipStream_t stream) {
    const float* hidden = (const float*)d_in[0];
    const int*   adj    = (const int*)d_in[1];
    const int*   mask   = (const int*)d_in[2];
    const float* W_Q    = (const float*)d_in[3];
    // d_in[4]=W_K, d_in[5]=W_V unused (source bug preserved: k = v = q)
    const float* aparam = (const float*)d_in[6];
    const float* p_w1   = (const float*)d_in[7];
    const float* p_b1   = (const float*)d_in[8];
    const float* p_w2   = (const float*)d_in[9];
    const float* p_b2   = (const float*)d_in[10];
    const float* g_w1   = (const float*)d_in[11];
    const float* g_b1   = (const float*)d_in[12];
    const float* g_w2   = (const float*)d_in[13];
    const float* g_b2   = (const float*)d_in[14];
    float* out = (float*)d_out;
    float* qws = (float*)d_ws;   // [2048][128] f32 = 1 MB

    hete_qproj<<<BB * NN, 128, 0, stream>>>(hidden, mask, W_Q, qws);
    hete_fused<<<BB * 32, 256, 0, stream>>>(qws, adj, aparam,
                                            p_w1, p_b1, p_w2, p_b2,
                                            g_w1, g_b1, g_w2, g_b2, out);
}

// Round 3
// 106.250 us; speedup vs baseline: 1.1315x; 1.0501x over previous
//
#include <hip/hip_runtime.h>
#include <math.h>

#define BB 16
#define NN 128
#define DD 128
#define NEGV (-9e15f)
#define SLOPE 0.2f

typedef __attribute__((ext_vector_type(8))) short bf16x8;
typedef __attribute__((ext_vector_type(4))) float f32x4;

__device__ __forceinline__ float fast_tanh(float x) {
    float e = __expf(2.f * x);
    return 1.f - 2.f / (e + 1.f);
}
__device__ __forceinline__ float bf2f(short s) {
    union { unsigned u; float f; } v; v.u = ((unsigned)(unsigned short)s) << 16; return v.f;
}
__device__ __forceinline__ short f2bf(float f) {
    union { float f; unsigned u; } v; v.f = f;
    unsigned r = v.u + 0x7FFF + ((v.u >> 16) & 1);   // RNE
    return (short)(r >> 16);
}
// byte offset of 16B chunk `oct` in row `row` of a [*][128] bf16 LDS array, XOR-swizzled
__device__ __forceinline__ int swz(int row, int oct) { return row * 256 + ((oct ^ (row & 7)) << 4); }

// ---------------- K1: typed Q projection (unchanged from R2 — proven) ----------------
__global__ __launch_bounds__(128) void hete_qproj(
    const float* __restrict__ hidden, const int* __restrict__ mask,
    const float* __restrict__ WQ, float* __restrict__ q)
{
    const int r = blockIdx.x;
    const int d = threadIdx.x;
    __shared__ float h[DD];
    h[d] = hidden[r * DD + d];
    __syncthreads();
    const int t = mask[r];
    if (t == 0) { q[r * DD + d] = 0.f; return; }
    const float* W = WQ + t * DD * DD;
    float acc = 0.f;
#pragma unroll 8
    for (int k = 0; k < DD; ++k)
        acc = fmaf(h[k], W[k * DD + d], acc);
    q[r * DD + d] = acc;
}

// ---------------- K_T: transpose p_w1 and g_w1 (once, into d_ws) ----------------
__global__ __launch_bounds__(256) void transpose2(
    const float* __restrict__ A, const float* __restrict__ B,
    float* __restrict__ AT, float* __restrict__ BT)
{
    __shared__ float t[16][17];
    const int mat = blockIdx.x >> 6, tile = blockIdx.x & 63;
    const int tr = tile >> 3, tc = tile & 7;
    const float* S = mat ? B : A;
    float* D = mat ? BT : AT;
    const int r = threadIdx.x >> 4, c = threadIdx.x & 15;
    t[r][c] = S[(tr * 16 + r) * DD + tc * 16 + c];
    __syncthreads();
    D[(tc * 16 + r) * DD + tr * 16 + c] = t[c][r];
}

// ---------------- K2: fused MFMA attention + gates ----------------
// grid = 16 batches x 16 chunks (8 rows), 512 threads = 8 waves.
// LDS layout (byte offsets into smem):
constexpr int QH_   = 0;       // [128][128] bf16 q-hi (swz)   — aliased by W1T-hi in gate phase
constexpr int QL_   = 32768;   // [128][128] bf16 q-lo (swz)   — aliased by W1T-lo
constexpr int QCHH_ = 65536;   // [16][128] bf16 chunk-hi (rows 8..15 zero)
constexpr int QCHL_ = 69632;   // [16][128] bf16 chunk-lo
constexpr int QA_   = 73728;   // [32][128] bf16 q*a_t (t*8+r8) — aliased by X [16][128] bf16
constexpr int ADJ_  = 81920;   // [8][128] int
constexpr int WMAT_ = 86016;   // [8][128] float4 (wH, wT, gw, -)
constexpr int RO_   = 102400;  // [3][8][128] f32: homo(->local)/hete/global
constexpr int RED_  = 114688;  // [8][8][4] f32
constexpr int GRED_ = 115712;  // [8][16] f32
constexpr int ENR_  = 116224;  // [16] f32
constexpr int SMEM_ = 116288;

#define MFMA(a, b, c) __builtin_amdgcn_mfma_f32_16x16x32_bf16((a), (b), (c), 0, 0, 0)

__global__ __launch_bounds__(512) void hete_fused(
    const float* __restrict__ q, const int* __restrict__ adj,
    const float* __restrict__ aparam,
    const float* __restrict__ w1t, const float* __restrict__ g1t,
    const float* __restrict__ p_b1, const float* __restrict__ p_w2, const float* __restrict__ p_b2,
    const float* __restrict__ g_b1, const float* __restrict__ g_w2, const float* __restrict__ g_b2,
    float* __restrict__ out)
{
    __shared__ __align__(16) char smem[SMEM_];
    const int tid   = threadIdx.x;
    const int b     = blockIdx.x >> 4;
    const int chunk = blockIdx.x & 15;
    const int wv    = tid >> 6;
    const int lane  = tid & 63;
    const int l15   = lane & 15;
    const int l4    = lane >> 4;
    const int i7    = lane & 7;
    const float* qb = q + b * NN * DD;

    // ================= Phase 0: staging =================
#pragma unroll
    for (int it = 0; it < 4; ++it) {          // q -> qh/ql (2048 octets)
        int oct = it * 512 + tid;
        int row = oct >> 4, o = oct & 15;
        const f32x4* src = (const f32x4*)(qb + row * DD + o * 8);
        f32x4 x0 = src[0], x1 = src[1];
        float xs[8] = {x0.x, x0.y, x0.z, x0.w, x1.x, x1.y, x1.z, x1.w};
        bf16x8 h, l;
#pragma unroll
        for (int e = 0; e < 8; ++e) { short hb = f2bf(xs[e]); h[e] = hb; l[e] = f2bf(xs[e] - bf2f(hb)); }
        *(bf16x8*)(smem + QH_ + swz(row, o)) = h;
        *(bf16x8*)(smem + QL_ + swz(row, o)) = l;
    }
    if (tid < 256) {                          // chunk copy, rows 8..15 zeroed
        int n = tid >> 4, o = tid & 15;
        bf16x8 h = {0,0,0,0,0,0,0,0}, l = {0,0,0,0,0,0,0,0};
        if (n < 8) {
            const f32x4* src = (const f32x4*)(qb + (chunk * 8 + n) * DD + o * 8);
            f32x4 x0 = src[0], x1 = src[1];
            float xs[8] = {x0.x, x0.y, x0.z, x0.w, x1.x, x1.y, x1.z, x1.w};
#pragma unroll
            for (int e = 0; e < 8; ++e) { short hb = f2bf(xs[e]); h[e] = hb; l[e] = f2bf(xs[e] - bf2f(hb)); }
        }
        *(bf16x8*)(smem + QCHH_ + swz(n, o)) = h;
        *(bf16x8*)(smem + QCHL_ + swz(n, o)) = l;
    }
    {                                          // qa: rows (t*8+r8), single bf16
        int nr = tid >> 4, o = tid & 15;
        int t = nr >> 3, r8 = nr & 7;
        const f32x4* sq = (const f32x4*)(qb + (chunk * 8 + r8) * DD + o * 8);
        const f32x4* sa = (const f32x4*)(aparam + t * DD + o * 8);
        f32x4 q0 = sq[0], q1 = sq[1], a0 = sa[0], a1 = sa[1];
        bf16x8 v;
        v[0] = f2bf(q0.x * a0.x); v[1] = f2bf(q0.y * a0.y);
        v[2] = f2bf(q0.z * a0.z); v[3] = f2bf(q0.w * a0.w);
        v[4] = f2bf(q1.x * a1.x); v[5] = f2bf(q1.y * a1.y);
        v[6] = f2bf(q1.z * a1.z); v[7] = f2bf(q1.w * a1.w);
        *(bf16x8*)(smem + QA_ + swz(nr, o)) = v;
    }
    if (tid < 256) {                           // adj chunk
        const int4* s = (const int4*)(adj + (b * NN + chunk * 8) * NN);
        ((int4*)(smem + ADJ_))[tid] = s[tid];
    }
    __syncthreads();

    // ================= Phase B: score MFMAs (S^T and hm^T) =================
    // wave wv = m-tile (j = wv*16 + ...); D[j][i]: row=j (A=q rows), col=i (B=chunk rows)
    f32x4 accS  = {0.f, 0.f, 0.f, 0.f};
    f32x4 accH0 = {0.f, 0.f, 0.f, 0.f};   // qa cols 0..15  (t=0,1)
    f32x4 accH1 = {0.f, 0.f, 0.f, 0.f};   // qa cols 16..31 (t=2,3)
    {
        const int arow = wv * 16 + l15;
#pragma unroll
        for (int ks = 0; ks < 4; ++ks) {
            int o = ks * 4 + l4;
            bf16x8 Ah = *(const bf16x8*)(smem + QH_  + swz(arow, o));
            bf16x8 Al = *(const bf16x8*)(smem + QL_  + swz(arow, o));
            bf16x8 Bh = *(const bf16x8*)(smem + QCHH_ + swz(l15, o));
            bf16x8 Bl = *(const bf16x8*)(smem + QCHL_ + swz(l15, o));
            bf16x8 Q0 = *(const bf16x8*)(smem + QA_ + swz(l15, o));
            bf16x8 Q1 = *(const bf16x8*)(smem + QA_ + swz(16 + l15, o));
            accS  = MFMA(Ah, Bh, accS);
            accS  = MFMA(Ah, Bl, accS);
            accS  = MFMA(Al, Bh, accS);
            accH0 = MFMA(Ah, Q0, accH0);
            accH0 = MFMA(Al, Q0, accH0);
            accH1 = MFMA(Ah, Q1, accH1);
            accH1 = MFMA(Al, Q1, accH1);
        }
    }

    // ================= Phase C: epilogue + softmax + weights =================
    {
        f32x4 pH0, pH1;                        // partner exchange: odd edge-types
#pragma unroll
        for (int r = 0; r < 4; ++r) {
            pH0[r] = __shfl_xor(accH0[r], 8);
            pH1[r] = __shfl_xor(accH1[r], 8);
        }
        const bool low = (l15 < 8);
        const int* adjl = (const int*)(smem + ADJ_);
        float aHv[4], sTv[4], gwv[4];
#pragma unroll
        for (int r = 0; r < 4; ++r) {
            int j = wv * 16 + l4 * 4 + r;
            int adjv = adjl[i7 * NN + j];
            float s = accS[r];
            float hm = (adjv <= 2) ? ((adjv == 1) ? accH0[r] : pH0[r])
                                   : ((adjv == 3) ? accH1[r] : pH1[r]);
            bool inH = (adjv >= 1) & (adjv <= 4);
            bool inT = (adjv == 1) | (adjv >= 5);
            float aH = inH ? (hm > 0.f ? hm : SLOPE * hm) : NEGV;     // homo: lrelu then mask
            float sT = inT ? s : NEGV; sT = sT > 0.f ? sT : SLOPE * sT; // hete: mask then lrelu
            aHv[r] = aH; sTv[r] = sT; gwv[r] = fast_tanh(s);
        }
        float mH = fmaxf(fmaxf(aHv[0], aHv[1]), fmaxf(aHv[2], aHv[3]));
        float mT = fmaxf(fmaxf(sTv[0], sTv[1]), fmaxf(sTv[2], sTv[3]));
        mH = fmaxf(mH, __shfl_xor(mH, 16)); mH = fmaxf(mH, __shfl_xor(mH, 32));
        mT = fmaxf(mT, __shfl_xor(mT, 16)); mT = fmaxf(mT, __shfl_xor(mT, 32));
        float* red = (float*)(smem + RED_);
        if (low && l4 == 0) { red[(wv * 8 + l15) * 4 + 0] = mH; red[(wv * 8 + l15) * 4 + 1] = mT; }
        __syncthreads();
        float gmH = NEGV, gmT = NEGV;
#pragma unroll
        for (int w = 0; w < 8; ++w) {
            gmH = fmaxf(gmH, red[(w * 8 + i7) * 4 + 0]);
            gmT = fmaxf(gmT, red[(w * 8 + i7) * 4 + 1]);
        }
        float eH[4], eT[4], pHs = 0.f, pTs = 0.f;
#pragma unroll
        for (int r = 0; r < 4; ++r) {
            eH[r] = __expf(aHv[r] - gmH); pHs += eH[r];
            eT[r] = __expf(sTv[r] - gmT); pTs += eT[r];
        }
        pHs += __shfl_xor(pHs, 16); pHs += __shfl_xor(pHs, 32);
        pTs += __shfl_xor(pTs, 16); pTs += __shfl_xor(pTs, 32);
        if (low && l4 == 0) { red[(wv * 8 + l15) * 4 + 2] = pHs; red[(wv * 8 + l15) * 4 + 3] = pTs; }
        __syncthreads();
        float sH = 0.f, sT2 = 0.f;
#pragma unroll
        for (int w = 0; w < 8; ++w) {
            sH  += red[(w * 8 + i7) * 4 + 2];
            sT2 += red[(w * 8 + i7) * 4 + 3];
        }
        float invH = 1.f / sH, invT = 1.f / sT2;
        if (low) {
            float4* wm = (float4*)(smem + WMAT_);
#pragma unroll
            for (int r = 0; r < 4; ++r) {
                int j = wv * 16 + l4 * 4 + r;
                wm[l15 * NN + j] = make_float4(eH[r] * invH, eT[r] * invT, gwv[r], 0.f);
            }
        }
        __syncthreads();
    }

    // ================= Phase D: weighted sums (VALU, q-hi) =================
    {
        // wave wv = output row i; lanes: l4 = j-quarter, l15 = d-octet
        float a0[8] = {0,0,0,0,0,0,0,0}, a1[8] = {0,0,0,0,0,0,0,0}, a2[8] = {0,0,0,0,0,0,0,0};
        const float4* wm = (const float4*)(smem + WMAT_) + wv * NN;
#pragma unroll 4
        for (int jj = 0; jj < 32; ++jj) {
            int j = l4 * 32 + jj;
            bf16x8 qv = *(const bf16x8*)(smem + QH_ + swz(j, l15));
            float4 w4 = wm[j];
#pragma unroll
            for (int e = 0; e < 8; ++e) {
                float qf = bf2f(qv[e]);
                a0[e] = fmaf(w4.x, qf, a0[e]);
                a1[e] = fmaf(w4.y, qf, a1[e]);
                a2[e] = fmaf(w4.z, qf, a2[e]);
            }
        }
#pragma unroll
        for (int e = 0; e < 8; ++e) {
            a0[e] += __shfl_xor(a0[e], 16); a0[e] += __shfl_xor(a0[e], 32);
            a1[e] += __shfl_xor(a1[e], 16); a1[e] += __shfl_xor(a1[e], 32);
            a2[e] += __shfl_xor(a2[e], 16); a2[e] += __shfl_xor(a2[e], 32);
        }
        if (lane < 16) {
            float* ro = (float*)(smem + RO_);
            f32x4 v;
            v = (f32x4){a0[0],a0[1],a0[2],a0[3]}; *(f32x4*)(ro + (0*8+wv)*DD + lane*8)     = v;
            v = (f32x4){a0[4],a0[5],a0[6],a0[7]}; *(f32x4*)(ro + (0*8+wv)*DD + lane*8 + 4) = v;
            v = (f32x4){a1[0],a1[1],a1[2],a1[3]}; *(f32x4*)(ro + (1*8+wv)*DD + lane*8)     = v;
            v = (f32x4){a1[4],a1[5],a1[6],a1[7]}; *(f32x4*)(ro + (1*8+wv)*DD + lane*8 + 4) = v;
            v = (f32x4){a2[0],a2[1],a2[2],a2[3]}; *(f32x4*)(ro + (2*8+wv)*DD + lane*8)     = v;
            v = (f32x4){a2[4],a2[5],a2[6],a2[7]}; *(f32x4*)(ro + (2*8+wv)*DD + lane*8 + 4) = v;
        }
        __syncthreads();
    }

    // ================= Phase E: gate MLPs via MFMA =================
    float* ro  = (float*)(smem + RO_);
    float* gred = (float*)(smem + GRED_);
    float* enr  = (float*)(smem + ENR_);
#pragma unroll
    for (int stage = 0; stage < 2; ++stage) {
        const float* wt  = stage ? g1t : w1t;
        const float* b1  = stage ? g_b1 : p_b1;
        const float* w2  = stage ? g_w2 : p_w2;
        const float* b2  = stage ? g_b2 : p_b2;
        // stage W^T (hi/lo) over QH/QL, X over QA
#pragma unroll
        for (int it = 0; it < 4; ++it) {
            int oct = it * 512 + tid;
            int row = oct >> 4, o = oct & 15;
            const f32x4* src = (const f32x4*)(wt + row * DD + o * 8);
            f32x4 x0 = src[0], x1 = src[1];
            float xs[8] = {x0.x, x0.y, x0.z, x0.w, x1.x, x1.y, x1.z, x1.w};
            bf16x8 h, l;
#pragma unroll
            for (int e = 0; e < 8; ++e) { short hb = f2bf(xs[e]); h[e] = hb; l[e] = f2bf(xs[e] - bf2f(hb)); }
            *(bf16x8*)(smem + QH_ + swz(row, o)) = h;
            *(bf16x8*)(smem + QL_ + swz(row, o)) = l;
        }
        if (tid < 256) {   // X rows: e = row*2 + gate; stage0 gates (ro0, ro1), stage1 (ro0, ro2)
            int e = tid >> 4, o = tid & 15;
            int row = e >> 1;
            int p = (e & 1) ? (stage ? 2 : 1) : 0;
            const float* x = ro + (p * 8 + row) * DD + o * 8;
            f32x4 x0 = *(const f32x4*)x, x1 = *(const f32x4*)(x + 4);
            bf16x8 v;
            v[0]=f2bf(x0.x); v[1]=f2bf(x0.y); v[2]=f2bf(x0.z); v[3]=f2bf(x0.w);
            v[4]=f2bf(x1.x); v[5]=f2bf(x1.y); v[6]=f2bf(x1.z); v[7]=f2bf(x1.w);
            *(bf16x8*)(smem + QA_ + swz(e, o)) = v;
        }
        __syncthreads();
        // out(e, u) = X @ W : wave wv = u-tile
        f32x4 accG = {0.f, 0.f, 0.f, 0.f};
        const int urow = wv * 16 + l15;
#pragma unroll
        for (int ks = 0; ks < 4; ++ks) {
            int o = ks * 4 + l4;
            bf16x8 Ax = *(const bf16x8*)(smem + QA_ + swz(l15, o));
            bf16x8 Wh = *(const bf16x8*)(smem + QH_ + swz(urow, o));
            bf16x8 Wl = *(const bf16x8*)(smem + QL_ + swz(urow, o));
            accG = MFMA(Ax, Wh, accG);
            accG = MFMA(Ax, Wl, accG);
        }
        float b1u = b1[urow], w2u = w2[urow];
        float pe[4];
#pragma unroll
        for (int r = 0; r < 4; ++r) {
            float h = accG[r] + b1u;
            h = h > 0.f ? h : 0.f;
            pe[r] = h * w2u;
        }
#pragma unroll
        for (int off = 1; off <= 8; off <<= 1) {
#pragma unroll
            for (int r = 0; r < 4; ++r) pe[r] += __shfl_xor(pe[r], off);
        }
        if (l15 == 0) {
#pragma unroll
            for (int r = 0; r < 4; ++r) gred[wv * 16 + l4 * 4 + r] = pe[r];
        }
        __syncthreads();
        if (tid < 16) {
            float s = b2[0];
#pragma unroll
            for (int w = 0; w < 8; ++w) s += gred[w * 16 + tid];
            enr[tid] = s;
        }
        __syncthreads();
        if (stage == 0) {
            // local = softmax2(homo, hete) -> overwrite ro[0]
#pragma unroll
            for (int k = 0; k < 2; ++k) {
                int idx = k * 512 + tid;
                int row = idx >> 7, d = idx & 127;
                float e0 = enr[row * 2], e1 = enr[row * 2 + 1];
                float m = fmaxf(e0, e1);
                float x0 = __expf(e0 - m), x1 = __expf(e1 - m);
                float inv = 1.f / (x0 + x1);
                ro[(0 * 8 + row) * DD + d] =
                    (x0 * ro[(0 * 8 + row) * DD + d] + x1 * ro[(1 * 8 + row) * DD + d]) * inv;
            }
            __syncthreads();
        } else {
            // final = softmax2(local, global) -> global write
#pragma unroll
            for (int k = 0; k < 2; ++k) {
                int idx = k * 512 + tid;
                int row = idx >> 7, d = idx & 127;
                float e0 = enr[row * 2], e1 = enr[row * 2 + 1];
                float m = fmaxf(e0, e1);
                float x0 = __expf(e0 - m), x1 = __expf(e1 - m);
                float inv = 1.f / (x0 + x1);
                float val = (x0 * ro[(0 * 8 + row) * DD + d] + x1 * ro[(2 * 8 + row) * DD + d]) * inv;
                out[(b * NN + chunk * 8 + row) * DD + d] = val;
            }
        }
    }
}

extern "C" void kernel_launch(void* const* d_in, const int* in_sizes, int n_in,
                              void* d_out, int out_size, void* d_ws, size_t ws_size,
                              hipStream_t stream) {
    const float* hidden = (const float*)d_in[0];
    const int*   adjp   = (const int*)d_in[1];
    const int*   maskp  = (const int*)d_in[2];
    const float* W_Q    = (const float*)d_in[3];
    // d_in[4]=W_K, d_in[5]=W_V unused (source bug preserved: k = v = q)
    const float* aparam = (const float*)d_in[6];
    const float* p_w1   = (const float*)d_in[7];
    const float* p_b1   = (const float*)d_in[8];
    const float* p_w2   = (const float*)d_in[9];
    const float* p_b2   = (const float*)d_in[10];
    const float* g_w1   = (const float*)d_in[11];
    const float* g_b1   = (const float*)d_in[12];
    const float* g_w2   = (const float*)d_in[13];
    const float* g_b2   = (const float*)d_in[14];
    float* out = (float*)d_out;

    float* qws = (float*)d_ws;                              // [2048][128] f32 = 1 MB
    float* w1t = (float*)((char*)d_ws + (1u << 20));        // [128][128] f32 = 64 KB
    float* g1t = (float*)((char*)d_ws + (1u << 20) + 65536);

    hete_qproj<<<BB * NN, 128, 0, stream>>>(hidden, maskp, W_Q, qws);
    transpose2<<<128, 256, 0, stream>>>(p_w1, g_w1, w1t, g1t);
    hete_fused<<<BB * 16, 512, 0, stream>>>(qws, adjp, aparam, w1t, g1t,
                                            p_b1, p_w2, p_b2, g_b1, g_w2, g_b2, out);
}

// Round 4
// 101.797 us; speedup vs baseline: 1.1809x; 1.0437x over previous
//
#include <hip/hip_runtime.h>
#include <math.h>

#define BB 16
#define NN 128
#define DD 128
#define NEGV (-9e15f)
#define SLOPE 0.2f

typedef __attribute__((ext_vector_type(8))) short bf16x8;
typedef __attribute__((ext_vector_type(4))) float f32x4;

__device__ __forceinline__ float fast_tanh(float x) {
    float e = __expf(2.f * x);
    return 1.f - 2.f / (e + 1.f);
}
__device__ __forceinline__ float bf2f(short s) {
    union { unsigned u; float f; } v; v.u = ((unsigned)(unsigned short)s) << 16; return v.f;
}
__device__ __forceinline__ short f2bf(float f) {
    union { float f; unsigned u; } v; v.f = f;
    unsigned r = v.u + 0x7FFF + ((v.u >> 16) & 1);   // RNE
    return (short)(r >> 16);
}
// byte offset of 16B chunk `oct` in row `row` of a [*][128] bf16 LDS array, XOR-swizzled
__device__ __forceinline__ int swz(int row, int oct) { return row * 256 + ((oct ^ (row & 7)) << 4); }

// ---------------- K1: typed Q projection + W1 transposes (merged) ----------------
// blocks [0, 2048): one q row each, float4 W reads, 4 outputs/thread.
// blocks [2048, 2176): 16x16 transpose tiles of p_w1 / g_w1 into d_ws.
__global__ __launch_bounds__(128) void hete_pre(
    const float* __restrict__ hidden, const int* __restrict__ mask,
    const float* __restrict__ WQ,
    const float* __restrict__ p_w1, const float* __restrict__ g_w1,
    float* __restrict__ q, float* __restrict__ w1t, float* __restrict__ g1t)
{
    const int bid = blockIdx.x;
    const int tid = threadIdx.x;
    if (bid < BB * NN) {
        __shared__ float h[DD];
        __shared__ __align__(16) float part[32][4];
        const int r = bid;
        h[tid] = hidden[r * DD + tid];
        __syncthreads();
        const int t = mask[r];                 // uniform per block
        const int dq = tid & 31, ks = tid >> 5;
        if (t == 0) {
            if (tid < 32) *(f32x4*)(q + r * DD + tid * 4) = (f32x4){0.f, 0.f, 0.f, 0.f};
            return;
        }
        const float* W = WQ + t * DD * DD + dq * 4;
        f32x4 acc = {0.f, 0.f, 0.f, 0.f};
#pragma unroll 8
        for (int k = ks * 32; k < ks * 32 + 32; ++k) {
            f32x4 w4 = *(const f32x4*)(W + k * DD);   // coalesced: 32 lanes x 16B
            float hk = h[k];
            acc.x = fmaf(hk, w4.x, acc.x);
            acc.y = fmaf(hk, w4.y, acc.y);
            acc.z = fmaf(hk, w4.z, acc.z);
            acc.w = fmaf(hk, w4.w, acc.w);
        }
        // combine ks pairs within each wave (lanes 32 apart)
        acc.x += __shfl_xor(acc.x, 32);
        acc.y += __shfl_xor(acc.y, 32);
        acc.z += __shfl_xor(acc.z, 32);
        acc.w += __shfl_xor(acc.w, 32);
        if (tid >= 64 && tid < 96)             // wave1 holds ks{2,3} sum
            *(f32x4*)&part[dq][0] = acc;
        __syncthreads();
        if (tid < 32) {                        // wave0 lanes hold ks{0,1} sum
            f32x4 o = *(const f32x4*)&part[dq][0];
            acc.x += o.x; acc.y += o.y; acc.z += o.z; acc.w += o.w;
            *(f32x4*)(q + r * DD + dq * 4) = acc;
        }
    } else {
        __shared__ float tb[16][17];
        const int bid2 = bid - BB * NN;
        const int mat = bid2 >> 6, tile = bid2 & 63;
        const int tr = tile >> 3, tc = tile & 7;
        const float* S = mat ? g_w1 : p_w1;
        float* Dst = mat ? g1t : w1t;
        const int rr = tid >> 4, c = tid & 15; // rr 0..7
        tb[rr][c]     = S[(tr * 16 + rr) * DD + tc * 16 + c];
        tb[rr + 8][c] = S[(tr * 16 + rr + 8) * DD + tc * 16 + c];
        __syncthreads();
        Dst[(tc * 16 + rr) * DD + tr * 16 + c]     = tb[c][rr];
        Dst[(tc * 16 + rr + 8) * DD + tr * 16 + c] = tb[c][rr + 8];
    }
}

// ---------------- K2: fused MFMA attention + gates (unchanged from R3 — proven) ----------------
// grid = 16 batches x 16 chunks (8 rows), 512 threads = 8 waves.
constexpr int QH_   = 0;       // [128][128] bf16 q-hi (swz)   — aliased by W1T-hi in gate phase
constexpr int QL_   = 32768;   // [128][128] bf16 q-lo (swz)   — aliased by W1T-lo
constexpr int QCHH_ = 65536;   // [16][128] bf16 chunk-hi (rows 8..15 zero)
constexpr int QCHL_ = 69632;   // [16][128] bf16 chunk-lo
constexpr int QA_   = 73728;   // [32][128] bf16 q*a_t (t*8+r8) — aliased by X [16][128] bf16
constexpr int ADJ_  = 81920;   // [8][128] int
constexpr int WMAT_ = 86016;   // [8][128] float4 (wH, wT, gw, -)
constexpr int RO_   = 102400;  // [3][8][128] f32: homo(->local)/hete/global
constexpr int RED_  = 114688;  // [8][8][4] f32
constexpr int GRED_ = 115712;  // [8][16] f32
constexpr int ENR_  = 116224;  // [16] f32
constexpr int SMEM_ = 116288;

#define MFMA(a, b, c) __builtin_amdgcn_mfma_f32_16x16x32_bf16((a), (b), (c), 0, 0, 0)

__global__ __launch_bounds__(512) void hete_fused(
    const float* __restrict__ q, const int* __restrict__ adj,
    const float* __restrict__ aparam,
    const float* __restrict__ w1t, const float* __restrict__ g1t,
    const float* __restrict__ p_b1, const float* __restrict__ p_w2, const float* __restrict__ p_b2,
    const float* __restrict__ g_b1, const float* __restrict__ g_w2, const float* __restrict__ g_b2,
    float* __restrict__ out)
{
    __shared__ __align__(16) char smem[SMEM_];
    const int tid   = threadIdx.x;
    const int b     = blockIdx.x >> 4;
    const int chunk = blockIdx.x & 15;
    const int wv    = tid >> 6;
    const int lane  = tid & 63;
    const int l15   = lane & 15;
    const int l4    = lane >> 4;
    const int i7    = lane & 7;
    const float* qb = q + b * NN * DD;

    // ================= Phase 0: staging =================
#pragma unroll
    for (int it = 0; it < 4; ++it) {          // q -> qh/ql (2048 octets)
        int oct = it * 512 + tid;
        int row = oct >> 4, o = oct & 15;
        const f32x4* src = (const f32x4*)(qb + row * DD + o * 8);
        f32x4 x0 = src[0], x1 = src[1];
        float xs[8] = {x0.x, x0.y, x0.z, x0.w, x1.x, x1.y, x1.z, x1.w};
        bf16x8 h, l;
#pragma unroll
        for (int e = 0; e < 8; ++e) { short hb = f2bf(xs[e]); h[e] = hb; l[e] = f2bf(xs[e] - bf2f(hb)); }
        *(bf16x8*)(smem + QH_ + swz(row, o)) = h;
        *(bf16x8*)(smem + QL_ + swz(row, o)) = l;
    }
    if (tid < 256) {                          // chunk copy, rows 8..15 zeroed
        int n = tid >> 4, o = tid & 15;
        bf16x8 h = {0,0,0,0,0,0,0,0}, l = {0,0,0,0,0,0,0,0};
        if (n < 8) {
            const f32x4* src = (const f32x4*)(qb + (chunk * 8 + n) * DD + o * 8);
            f32x4 x0 = src[0], x1 = src[1];
            float xs[8] = {x0.x, x0.y, x0.z, x0.w, x1.x, x1.y, x1.z, x1.w};
#pragma unroll
            for (int e = 0; e < 8; ++e) { short hb = f2bf(xs[e]); h[e] = hb; l[e] = f2bf(xs[e] - bf2f(hb)); }
        }
        *(bf16x8*)(smem + QCHH_ + swz(n, o)) = h;
        *(bf16x8*)(smem + QCHL_ + swz(n, o)) = l;
    }
    {                                          // qa: rows (t*8+r8), single bf16
        int nr = tid >> 4, o = tid & 15;
        int t = nr >> 3, r8 = nr & 7;
        const f32x4* sq = (const f32x4*)(qb + (chunk * 8 + r8) * DD + o * 8);
        const f32x4* sa = (const f32x4*)(aparam + t * DD + o * 8);
        f32x4 q0 = sq[0], q1 = sq[1], a0 = sa[0], a1 = sa[1];
        bf16x8 v;
        v[0] = f2bf(q0.x * a0.x); v[1] = f2bf(q0.y * a0.y);
        v[2] = f2bf(q0.z * a0.z); v[3] = f2bf(q0.w * a0.w);
        v[4] = f2bf(q1.x * a1.x); v[5] = f2bf(q1.y * a1.y);
        v[6] = f2bf(q1.z * a1.z); v[7] = f2bf(q1.w * a1.w);
        *(bf16x8*)(smem + QA_ + swz(nr, o)) = v;
    }
    if (tid < 256) {                           // adj chunk
        const int4* s = (const int4*)(adj + (b * NN + chunk * 8) * NN);
        ((int4*)(smem + ADJ_))[tid] = s[tid];
    }
    __syncthreads();

    // ================= Phase B: score MFMAs (S^T and hm^T) =================
    f32x4 accS  = {0.f, 0.f, 0.f, 0.f};
    f32x4 accH0 = {0.f, 0.f, 0.f, 0.f};   // qa cols 0..15  (t=0,1)
    f32x4 accH1 = {0.f, 0.f, 0.f, 0.f};   // qa cols 16..31 (t=2,3)
    {
        const int arow = wv * 16 + l15;
#pragma unroll
        for (int ks = 0; ks < 4; ++ks) {
            int o = ks * 4 + l4;
            bf16x8 Ah = *(const bf16x8*)(smem + QH_  + swz(arow, o));
            bf16x8 Al = *(const bf16x8*)(smem + QL_  + swz(arow, o));
            bf16x8 Bh = *(const bf16x8*)(smem + QCHH_ + swz(l15, o));
            bf16x8 Bl = *(const bf16x8*)(smem + QCHL_ + swz(l15, o));
            bf16x8 Q0 = *(const bf16x8*)(smem + QA_ + swz(l15, o));
            bf16x8 Q1 = *(const bf16x8*)(smem + QA_ + swz(16 + l15, o));
            accS  = MFMA(Ah, Bh, accS);
            accS  = MFMA(Ah, Bl, accS);
            accS  = MFMA(Al, Bh, accS);
            accH0 = MFMA(Ah, Q0, accH0);
            accH0 = MFMA(Al, Q0, accH0);
            accH1 = MFMA(Ah, Q1, accH1);
            accH1 = MFMA(Al, Q1, accH1);
        }
    }

    // ================= Phase C: epilogue + softmax + weights =================
    {
        f32x4 pH0, pH1;                        // partner exchange: odd edge-types
#pragma unroll
        for (int r = 0; r < 4; ++r) {
            pH0[r] = __shfl_xor(accH0[r], 8);
            pH1[r] = __shfl_xor(accH1[r], 8);
        }
        const bool low = (l15 < 8);
        const int* adjl = (const int*)(smem + ADJ_);
        float aHv[4], sTv[4], gwv[4];
#pragma unroll
        for (int r = 0; r < 4; ++r) {
            int j = wv * 16 + l4 * 4 + r;
            int adjv = adjl[i7 * NN + j];
            float s = accS[r];
            float hm = (adjv <= 2) ? ((adjv == 1) ? accH0[r] : pH0[r])
                                   : ((adjv == 3) ? accH1[r] : pH1[r]);
            bool inH = (adjv >= 1) & (adjv <= 4);
            bool inT = (adjv == 1) | (adjv >= 5);
            float aH = inH ? (hm > 0.f ? hm : SLOPE * hm) : NEGV;       // homo: lrelu then mask
            float sT = inT ? s : NEGV; sT = sT > 0.f ? sT : SLOPE * sT; // hete: mask then lrelu
            aHv[r] = aH; sTv[r] = sT; gwv[r] = fast_tanh(s);
        }
        float mH = fmaxf(fmaxf(aHv[0], aHv[1]), fmaxf(aHv[2], aHv[3]));
        float mT = fmaxf(fmaxf(sTv[0], sTv[1]), fmaxf(sTv[2], sTv[3]));
        mH = fmaxf(mH, __shfl_xor(mH, 16)); mH = fmaxf(mH, __shfl_xor(mH, 32));
        mT = fmaxf(mT, __shfl_xor(mT, 16)); mT = fmaxf(mT, __shfl_xor(mT, 32));
        float* red = (float*)(smem + RED_);
        if (low && l4 == 0) { red[(wv * 8 + l15) * 4 + 0] = mH; red[(wv * 8 + l15) * 4 + 1] = mT; }
        __syncthreads();
        float gmH = NEGV, gmT = NEGV;
#pragma unroll
        for (int w = 0; w < 8; ++w) {
            gmH = fmaxf(gmH, red[(w * 8 + i7) * 4 + 0]);
            gmT = fmaxf(gmT, red[(w * 8 + i7) * 4 + 1]);
        }
        float eH[4], eT[4], pHs = 0.f, pTs = 0.f;
#pragma unroll
        for (int r = 0; r < 4; ++r) {
            eH[r] = __expf(aHv[r] - gmH); pHs += eH[r];
            eT[r] = __expf(sTv[r] - gmT); pTs += eT[r];
        }
        pHs += __shfl_xor(pHs, 16); pHs += __shfl_xor(pHs, 32);
        pTs += __shfl_xor(pTs, 16); pTs += __shfl_xor(pTs, 32);
        if (low && l4 == 0) { red[(wv * 8 + l15) * 4 + 2] = pHs; red[(wv * 8 + l15) * 4 + 3] = pTs; }
        __syncthreads();
        float sH = 0.f, sT2 = 0.f;
#pragma unroll
        for (int w = 0; w < 8; ++w) {
            sH  += red[(w * 8 + i7) * 4 + 2];
            sT2 += red[(w * 8 + i7) * 4 + 3];
        }
        float invH = 1.f / sH, invT = 1.f / sT2;
        if (low) {
            float4* wm = (float4*)(smem + WMAT_);
#pragma unroll
            for (int r = 0; r < 4; ++r) {
                int j = wv * 16 + l4 * 4 + r;
                wm[l15 * NN + j] = make_float4(eH[r] * invH, eT[r] * invT, gwv[r], 0.f);
            }
        }
        __syncthreads();
    }

    // ================= Phase D: weighted sums (VALU, q-hi) =================
    {
        float a0[8] = {0,0,0,0,0,0,0,0}, a1[8] = {0,0,0,0,0,0,0,0}, a2[8] = {0,0,0,0,0,0,0,0};
        const float4* wm = (const float4*)(smem + WMAT_) + wv * NN;
#pragma unroll 4
        for (int jj = 0; jj < 32; ++jj) {
            int j = l4 * 32 + jj;
            bf16x8 qv = *(const bf16x8*)(smem + QH_ + swz(j, l15));
            float4 w4 = wm[j];
#pragma unroll
            for (int e = 0; e < 8; ++e) {
                float qf = bf2f(qv[e]);
                a0[e] = fmaf(w4.x, qf, a0[e]);
                a1[e] = fmaf(w4.y, qf, a1[e]);
                a2[e] = fmaf(w4.z, qf, a2[e]);
            }
        }
#pragma unroll
        for (int e = 0; e < 8; ++e) {
            a0[e] += __shfl_xor(a0[e], 16); a0[e] += __shfl_xor(a0[e], 32);
            a1[e] += __shfl_xor(a1[e], 16); a1[e] += __shfl_xor(a1[e], 32);
            a2[e] += __shfl_xor(a2[e], 16); a2[e] += __shfl_xor(a2[e], 32);
        }
        if (lane < 16) {
            float* ro = (float*)(smem + RO_);
            f32x4 v;
            v = (f32x4){a0[0],a0[1],a0[2],a0[3]}; *(f32x4*)(ro + (0*8+wv)*DD + lane*8)     = v;
            v = (f32x4){a0[4],a0[5],a0[6],a0[7]}; *(f32x4*)(ro + (0*8+wv)*DD + lane*8 + 4) = v;
            v = (f32x4){a1[0],a1[1],a1[2],a1[3]}; *(f32x4*)(ro + (1*8+wv)*DD + lane*8)     = v;
            v = (f32x4){a1[4],a1[5],a1[6],a1[7]}; *(f32x4*)(ro + (1*8+wv)*DD + lane*8 + 4) = v;
            v = (f32x4){a2[0],a2[1],a2[2],a2[3]}; *(f32x4*)(ro + (2*8+wv)*DD + lane*8)     = v;
            v = (f32x4){a2[4],a2[5],a2[6],a2[7]}; *(f32x4*)(ro + (2*8+wv)*DD + lane*8 + 4) = v;
        }
        __syncthreads();
    }

    // ================= Phase E: gate MLPs via MFMA =================
    float* ro  = (float*)(smem + RO_);
    float* gred = (float*)(smem + GRED_);
    float* enr  = (float*)(smem + ENR_);
#pragma unroll
    for (int stage = 0; stage < 2; ++stage) {
        const float* wt  = stage ? g1t : w1t;
        const float* b1  = stage ? g_b1 : p_b1;
        const float* w2  = stage ? g_w2 : p_w2;
        const float* b2  = stage ? g_b2 : p_b2;
#pragma unroll
        for (int it = 0; it < 4; ++it) {
            int oct = it * 512 + tid;
            int row = oct >> 4, o = oct & 15;
            const f32x4* src = (const f32x4*)(wt + row * DD + o * 8);
            f32x4 x0 = src[0], x1 = src[1];
            float xs[8] = {x0.x, x0.y, x0.z, x0.w, x1.x, x1.y, x1.z, x1.w};
            bf16x8 h, l;
#pragma unroll
            for (int e = 0; e < 8; ++e) { short hb = f2bf(xs[e]); h[e] = hb; l[e] = f2bf(xs[e] - bf2f(hb)); }
            *(bf16x8*)(smem + QH_ + swz(row, o)) = h;
            *(bf16x8*)(smem + QL_ + swz(row, o)) = l;
        }
        if (tid < 256) {   // X rows: e = row*2 + gate; stage0 gates (ro0, ro1), stage1 (ro0, ro2)
            int e = tid >> 4, o = tid & 15;
            int row = e >> 1;
            int p = (e & 1) ? (stage ? 2 : 1) : 0;
            const float* x = ro + (p * 8 + row) * DD + o * 8;
            f32x4 x0 = *(const f32x4*)x, x1 = *(const f32x4*)(x + 4);
            bf16x8 v;
            v[0]=f2bf(x0.x); v[1]=f2bf(x0.y); v[2]=f2bf(x0.z); v[3]=f2bf(x0.w);
            v[4]=f2bf(x1.x); v[5]=f2bf(x1.y); v[6]=f2bf(x1.z); v[7]=f2bf(x1.w);
            *(bf16x8*)(smem + QA_ + swz(e, o)) = v;
        }
        __syncthreads();
        f32x4 accG = {0.f, 0.f, 0.f, 0.f};
        const int urow = wv * 16 + l15;
#pragma unroll
        for (int ks = 0; ks < 4; ++ks) {
            int o = ks * 4 + l4;
            bf16x8 Ax = *(const bf16x8*)(smem + QA_ + swz(l15, o));
            bf16x8 Wh = *(const bf16x8*)(smem + QH_ + swz(urow, o));
            bf16x8 Wl = *(const bf16x8*)(smem + QL_ + swz(urow, o));
            accG = MFMA(Ax, Wh, accG);
            accG = MFMA(Ax, Wl, accG);
        }
        float b1u = b1[urow], w2u = w2[urow];
        float pe[4];
#pragma unroll
        for (int r = 0; r < 4; ++r) {
            float h = accG[r] + b1u;
            h = h > 0.f ? h : 0.f;
            pe[r] = h * w2u;
        }
#pragma unroll
        for (int off = 1; off <= 8; off <<= 1) {
#pragma unroll
            for (int r = 0; r < 4; ++r) pe[r] += __shfl_xor(pe[r], off);
        }
        if (l15 == 0) {
#pragma unroll
            for (int r = 0; r < 4; ++r) gred[wv * 16 + l4 * 4 + r] = pe[r];
        }
        __syncthreads();
        if (tid < 16) {
            float s = b2[0];
#pragma unroll
            for (int w = 0; w < 8; ++w) s += gred[w * 16 + tid];
            enr[tid] = s;
        }
        __syncthreads();
        if (stage == 0) {
#pragma unroll
            for (int k = 0; k < 2; ++k) {
                int idx = k * 512 + tid;
                int row = idx >> 7, d = idx & 127;
                float e0 = enr[row * 2], e1 = enr[row * 2 + 1];
                float m = fmaxf(e0, e1);
                float x0 = __expf(e0 - m), x1 = __expf(e1 - m);
                float inv = 1.f / (x0 + x1);
                ro[(0 * 8 + row) * DD + d] =
                    (x0 * ro[(0 * 8 + row) * DD + d] + x1 * ro[(1 * 8 + row) * DD + d]) * inv;
            }
            __syncthreads();
        } else {
#pragma unroll
            for (int k = 0; k < 2; ++k) {
                int idx = k * 512 + tid;
                int row = idx >> 7, d = idx & 127;
                float e0 = enr[row * 2], e1 = enr[row * 2 + 1];
                float m = fmaxf(e0, e1);
                float x0 = __expf(e0 - m), x1 = __expf(e1 - m);
                float inv = 1.f / (x0 + x1);
                float val = (x0 * ro[(0 * 8 + row) * DD + d] + x1 * ro[(2 * 8 + row) * DD + d]) * inv;
                out[(b * NN + chunk * 8 + row) * DD + d] = val;
            }
        }
    }
}

extern "C" void kernel_launch(void* const* d_in, const int* in_sizes, int n_in,
                              void* d_out, int out_size, void* d_ws, size_t ws_size,
                              hipStream_t stream) {
    const float* hidden = (const float*)d_in[0];
    const int*   adjp   = (const int*)d_in[1];
    const int*   maskp  = (const int*)d_in[2];
    const float* W_Q    = (const float*)d_in[3];
    // d_in[4]=W_K, d_in[5]=W_V unused (source bug preserved: k = v = q)
    const float* aparam = (const float*)d_in[6];
    const float* p_w1   = (const float*)d_in[7];
    const float* p_b1   = (const float*)d_in[8];
    const float* p_w2   = (const float*)d_in[9];
    const float* p_b2   = (const float*)d_in[10];
    const float* g_w1   = (const float*)d_in[11];
    const float* g_b1   = (const float*)d_in[12];
    const float* g_w2   = (const float*)d_in[13];
    const float* g_b2   = (const float*)d_in[14];
    float* out = (float*)d_out;

    float* qws = (float*)d_ws;                              // [2048][128] f32 = 1 MB
    float* w1t = (float*)((char*)d_ws + (1u << 20));        // [128][128] f32 = 64 KB
    float* g1t = (float*)((char*)d_ws + (1u << 20) + 65536);

    hete_pre<<<BB * NN + 128, 128, 0, stream>>>(hidden, maskp, W_Q, p_w1, g_w1,
                                                qws, w1t, g1t);
    hete_fused<<<BB * 16, 512, 0, stream>>>(qws, adjp, aparam, w1t, g1t,
                                            p_b1, p_w2, p_b2, g_b1, g_w2, g_b2, out);
}